// Round 8
// baseline (94.981 us; speedup 1.0000x reference)
//
#include <hip/hip_runtime.h>
#include <stdint.h>

// ---------------------------------------------------------------------------
// SlidingAttentionModule: B=2, S=2048, D=1024, H=16, hd=64, window +-8
//   qkv = x @ w_qkv^T + b_qkv     (256^2 deep-pipeline bf16 MFMA GEMM)
//   attn: MFMA-tiled 16-query x 32-key sliding window, no max-subtraction
//   out = ctx @ w_out^T + b_out   (128^2 R5-proven bf16 MFMA GEMM, fp32 out)
// ---------------------------------------------------------------------------

typedef __bf16 bf16_t;
typedef bf16_t bf16x8 __attribute__((ext_vector_type(8)));
typedef unsigned short u16x8 __attribute__((ext_vector_type(8)));
typedef float f32x4 __attribute__((ext_vector_type(4)));

#define GLD16(g, l)                                                        \
  __builtin_amdgcn_global_load_lds(                                        \
      (const __attribute__((address_space(1))) void*)(g),                  \
      (__attribute__((address_space(3))) void*)(l), 16, 0, 0)

__device__ __forceinline__ unsigned short f2bf(float f) {
  unsigned int u = __float_as_uint(f);
  u += 0x7FFFu + ((u >> 16) & 1u);  // round-to-nearest-even
  return (unsigned short)(u >> 16);
}

__device__ __forceinline__ bf16x8 ld16(const unsigned short* p) {
  return __builtin_bit_cast(bf16x8, *reinterpret_cast<const u16x8*>(p));
}

// --- fp32 -> bf16 conversion of all three tensors, one launch ---------------
__global__ void cvt_all(const float* __restrict__ x, const float* __restrict__ wq,
                        const float* __restrict__ wo, unsigned short* __restrict__ xb,
                        unsigned short* __restrict__ wqb,
                        unsigned short* __restrict__ wob) {
  const int N0 = 1048576, N1 = 786432, N2 = 262144;  // float4 counts
  for (int i = blockIdx.x * blockDim.x + threadIdx.x; i < N0 + N1 + N2;
       i += gridDim.x * blockDim.x) {
    const float4* src;
    unsigned short* dst;
    int j;
    if (i < N0) { src = (const float4*)x; dst = xb; j = i; }
    else if (i < N0 + N1) { src = (const float4*)wq; dst = wqb; j = i - N0; }
    else { src = (const float4*)wo; dst = wob; j = i - N0 - N1; }
    const float4 f = src[j];
    ushort4 o;
    o.x = f2bf(f.x); o.y = f2bf(f.y); o.z = f2bf(f.z); o.w = f2bf(f.w);
    reinterpret_cast<ushort4*>(dst)[j] = o;
  }
}

// --- 256x256 deep-pipeline bf16 GEMM (QKV projection) -----------------------
// C[m,n] = sum_k A[m,k]*Bt[n,k] + bias[n]; scatter bf16 q/k [bh,s,64],
// v transposed [bh,d,2048].
// 8 waves: wr=wave>>2 (128-row half), wc=wave&3 (64-col quarter).
// LDS per buffer per matrix: 2 halves x [128][64] ushort in granule layout:
//   ushort idx = h*8192 + ((row&127)>>3)*512 + (row&7)*64 + (slot^(row&7))*8
//   staged linearly: unit (h,r): lane u -> row h*128+r*64+wave*8+(u>>3),
//   global slot (u&7)^(u>>3); dest = h*8192+r*4096+wave*512 (+lane*16B).
//   8 lanes span one 128B row segment (permuted within) -> coalesced.
// Pipeline (R5-proven skeleton): 2 buffers, 2 K-tiles in flight, counted
//   s_waitcnt vmcnt(8) at tile top (never 0 mid-loop), raw s_barrier pair,
//   stage(t+2) issued after the read-drain barrier, hidden under kh1 MFMAs.
// Per tile, 2 phases (kh=0,1): 12 ds_read_b128 -> lgkm(0)+sched_barrier ->
//   setprio(1) 32 MFMA setprio(0).
__global__ __launch_bounds__(512, 2) void gemm256_qkv(
    const unsigned short* __restrict__ A,   // [4096,1024] bf16 bits
    const unsigned short* __restrict__ Bt,  // [3072,1024] bf16 bits
    const float* __restrict__ bias,         // [3072]
    unsigned short* __restrict__ Cq, unsigned short* __restrict__ Ck,
    unsigned short* __restrict__ Cv) {
  __shared__ unsigned short sA[2][16384];
  __shared__ unsigned short sB[2][16384];

  const int K = 1024;
  const int tid = threadIdx.x;
  const int wave = tid >> 6;
  const int lane = tid & 63;
  const int bid = blockIdx.x;
  const int m0 = (bid & 15) << 8;   // 16 m-tiles
  const int n0 = (bid >> 4) << 8;   // 12 n-tiles

  const int wr = wave >> 2;  // 0..1
  const int wc = wave & 3;   // 0..3

  f32x4 acc[8][4] = {};

  // staging source
  const int srow8 = (wave << 3) + (lane >> 3);            // 0..63
  const int sslot = ((lane & 7) ^ (lane >> 3)) << 3;      // elem off in row
  const unsigned short* Ag = A + (size_t)(m0 + srow8) * K + sslot;
  const unsigned short* Bg = Bt + (size_t)(n0 + srow8) * K + sslot;
  const int wdst = wave * 512;

  const int T = 16;  // K/64

  auto stage = [&](int t, int b) {
#pragma unroll
    for (int h = 0; h < 2; ++h)
#pragma unroll
      for (int r = 0; r < 2; ++r) {
        const size_t go = (size_t)(h * 128 + r * 64) * K + t * 64;
        const int lo = h * 8192 + r * 4096 + wdst;
        GLD16(Ag + go, &sA[b][lo]);
        GLD16(Bg + go, &sB[b][lo]);
      }
  };

  stage(0, 0);
  stage(1, 1);  // 16 loads/thread in flight

  const int kg = lane >> 4;
  const int l7 = lane & 7;
  // read bases (ushort idx), kh adds ^32 via +kh*? : slot_eff(kh)=((kh<<2)|kg)^l7
  //   -> byteswizzled: ((kg^l7)<<3) ^ (kh<<5)
  const int a0 = wr * 8192 + (lane & 15) * 64 + ((kg ^ l7) << 3);
  const int b0 =
      (wc >> 1) * 8192 + ((wc & 1) * 64 + (lane & 15)) * 64 + ((kg ^ l7) << 3);

  for (int t = 0; t < T; ++t) {
    if (t < T - 1)
      asm volatile("s_waitcnt vmcnt(8)" ::: "memory");
    else
      asm volatile("s_waitcnt vmcnt(0)" ::: "memory");
    __builtin_amdgcn_s_barrier();  // buf[b] landed; prior reads long done

    const int b = t & 1;
    const unsigned short* sAb = sA[b];
    const unsigned short* sBb = sB[b];

    // ---- phase kh=0 ----
    bf16x8 af[8], bf[4];
#pragma unroll
    for (int m = 0; m < 8; ++m) af[m] = ld16(&sAb[a0 + m * 1024]);
#pragma unroll
    for (int n = 0; n < 4; ++n) bf[n] = ld16(&sBb[b0 + n * 1024]);
    asm volatile("s_waitcnt lgkmcnt(0)" ::: "memory");
    __builtin_amdgcn_sched_barrier(0);
    __builtin_amdgcn_s_setprio(1);
#pragma unroll
    for (int m = 0; m < 8; ++m)
#pragma unroll
      for (int n = 0; n < 4; ++n)
        acc[m][n] = __builtin_amdgcn_mfma_f32_16x16x32_bf16(af[m], bf[n],
                                                            acc[m][n], 0, 0, 0);
    __builtin_amdgcn_s_setprio(0);

    // ---- phase kh=1 ----
    bf16x8 af1[8], bf1[4];
#pragma unroll
    for (int m = 0; m < 8; ++m) af1[m] = ld16(&sAb[(a0 ^ 32) + m * 1024]);
#pragma unroll
    for (int n = 0; n < 4; ++n) bf1[n] = ld16(&sBb[(b0 ^ 32) + n * 1024]);
    asm volatile("s_waitcnt lgkmcnt(0)" ::: "memory");
    __builtin_amdgcn_sched_barrier(0);
    __builtin_amdgcn_s_barrier();  // every wave done reading buf[b]

    if (t + 2 < T) stage(t + 2, b);  // overwrite safe; hidden under MFMAs

    __builtin_amdgcn_s_setprio(1);
#pragma unroll
    for (int m = 0; m < 8; ++m)
#pragma unroll
      for (int n = 0; n < 4; ++n)
        acc[m][n] = __builtin_amdgcn_mfma_f32_16x16x32_bf16(af1[m], bf1[n],
                                                            acc[m][n], 0, 0, 0);
    __builtin_amdgcn_s_setprio(0);
  }

  // epilogue: C/D layout col = lane&15, row = (lane>>4)*4 + reg  [m89]
#pragma unroll
  for (int m = 0; m < 8; ++m) {
    const int row0 = m0 + wr * 128 + m * 16 + ((lane >> 4) << 2);
#pragma unroll
    for (int n = 0; n < 4; ++n) {
      const int col = n0 + wc * 64 + n * 16 + (lane & 15);
      const float bb = bias[col];
#pragma unroll
      for (int r = 0; r < 4; ++r) {
        const int mm = row0 + r;
        const float val = acc[m][n][r] + bb;
        const int b2 = mm >> 11, s = mm & 2047;
        const int which = col >> 10, nn = col & 1023;
        const int h = nn >> 6, d = nn & 63;
        const int bh = (b2 << 4) + h;
        const unsigned short vb = f2bf(val);
        if (which == 0)
          Cq[((size_t)(bh * 2048 + s)) * 64 + d] = vb;
        else if (which == 1)
          Ck[((size_t)(bh * 2048 + s)) * 64 + d] = vb;
        else
          Cv[((size_t)(bh * 64 + d)) * 2048 + s] = vb;
      }
    }
  }
}

// --- 128x128 R5-proven GEMM (out projection, fp32 out) ----------------------
__global__ __launch_bounds__(256, 2) void gemm_bt(
    const unsigned short* __restrict__ A,   // [M,K] bf16 bits
    const unsigned short* __restrict__ Bt,  // [N,K] bf16 bits
    const float* __restrict__ bias,         // [N]
    float* __restrict__ Cp, int M, int N, int K, int gny) {
  __shared__ unsigned short sA[2][8192];
  __shared__ unsigned short sB[2][8192];

  const int tid = threadIdx.x;
  const int wave = tid >> 6;
  const int lane = tid & 63;

  const int nwg = gridDim.x;
  const int bid = blockIdx.x;
  const int cw = (nwg >> 3) / gny;
  const int xcd = bid & 7;
  const int idx = bid >> 3;
  const int m0 = (xcd * cw + idx % cw) * 128;
  const int n0 = (idx / cw) * 128;

  const int wr = wave >> 1;
  const int wc = wave & 1;

  f32x4 acc[4][4] = {};

  const int srow = (wave << 3) + (lane >> 3);
  const int sslot = ((lane & 7) ^ (lane >> 3)) << 3;
  const unsigned short* Ag = A + (size_t)(m0 + srow) * K + sslot;
  const unsigned short* Bg = Bt + (size_t)(n0 + srow) * K + sslot;
  const int wdst = wave * 512;

  const int T = K >> 6;

  auto stage = [&](int t, int b) {
#pragma unroll
    for (int r = 0; r < 4; ++r) {
      GLD16(Ag + (size_t)(r * 32) * K + t * 64, &sA[b][r * 2048 + wdst]);
      GLD16(Bg + (size_t)(r * 32) * K + t * 64, &sB[b][r * 2048 + wdst]);
    }
  };

  stage(0, 0);
  stage(1, 1);

  const int kg = lane >> 4;
  const int l7 = lane & 7;
  const int arr = wr * 64 + (lane & 15);
  const int brr = wc * 64 + (lane & 15);

  for (int t = 0; t < T; ++t) {
    if (t < T - 1)
      asm volatile("s_waitcnt vmcnt(8)" ::: "memory");
    else
      asm volatile("s_waitcnt vmcnt(0)" ::: "memory");
    __builtin_amdgcn_s_barrier();

    const int b = t & 1;
    const unsigned short* sAb = sA[b];
    const unsigned short* sBb = sB[b];
    bf16x8 af[2][4], bfr[2][4];
#pragma unroll
    for (int st = 0; st < 2; ++st) {
#pragma unroll
      for (int f = 0; f < 4; ++f) {
        const int se = ((st << 2) | kg) ^ l7;
        af[st][f] = ld16(&sAb[(arr + f * 16) * 64 + (se << 3)]);
        bfr[st][f] = ld16(&sBb[(brr + f * 16) * 64 + (se << 3)]);
      }
    }
    asm volatile("s_waitcnt lgkmcnt(0)" ::: "memory");
    __builtin_amdgcn_sched_barrier(0);
    __builtin_amdgcn_s_barrier();

    if (t + 2 < T) stage(t + 2, b);

#pragma unroll
    for (int st = 0; st < 2; ++st)
#pragma unroll
      for (int i = 0; i < 4; ++i)
#pragma unroll
        for (int j = 0; j < 4; ++j)
          acc[i][j] = __builtin_amdgcn_mfma_f32_16x16x32_bf16(
              af[st][i], bfr[st][j], acc[i][j], 0, 0, 0);
  }

#pragma unroll
  for (int i = 0; i < 4; ++i) {
    const int row0 = m0 + wr * 64 + i * 16 + ((lane >> 4) << 2);
#pragma unroll
    for (int j = 0; j < 4; ++j) {
      const int col = n0 + wc * 64 + j * 16 + (lane & 15);
      const float bb = bias[col];
#pragma unroll
      for (int r = 0; r < 4; ++r)
        Cp[(size_t)(row0 + r) * N + col] = acc[i][j][r] + bb;
    }
  }
}

// --- MFMA sliding attention: 1 wave = 16 queries x 32-key window ------------
// Q,K: [bh, s, 64] bf16.  Vt: [bh, d, 2048] bf16.  ctx out: [b, s, 1024] bf16.
__global__ __launch_bounds__(256) void attn_mfma(
    const unsigned short* __restrict__ Qb, const unsigned short* __restrict__ Kb,
    const unsigned short* __restrict__ Vt, unsigned short* __restrict__ ctx) {
  __shared__ unsigned short P[4][16][40];  // per-wave P tile, padded stride 40
  const int wave = threadIdx.x >> 6;
  const int lane = threadIdx.x & 63;
  const int gw = (blockIdx.x << 2) + wave;
  const int bh = gw >> 7;           // 0..31
  const int i0 = (gw & 127) << 4;   // query tile start
  const int qr = lane & 15;
  const int kg = lane >> 4;         // 0..3
  const int kc = kg << 3;           // k-offset

  const size_t qbase = ((size_t)(bh * 2048 + i0 + qr)) * 64;
  const bf16x8 aq0 = ld16(Qb + qbase + kc);
  const bf16x8 aq1 = ld16(Qb + qbase + 32 + kc);

  f32x4 sc0 = {0.f, 0.f, 0.f, 0.f}, sc1 = {0.f, 0.f, 0.f, 0.f};
  {
    const int ka0 = i0 - 8 + qr;
    const int ka1 = ka0 + 16;
    const int kcl0 = min(max(ka0, 0), 2047);
    const int kcl1 = min(max(ka1, 0), 2047);
    const unsigned short* K0 = Kb + ((size_t)(bh * 2048 + kcl0)) * 64;
    const unsigned short* K1 = Kb + ((size_t)(bh * 2048 + kcl1)) * 64;
    sc0 = __builtin_amdgcn_mfma_f32_16x16x32_bf16(aq0, ld16(K0 + kc), sc0, 0, 0, 0);
    sc0 = __builtin_amdgcn_mfma_f32_16x16x32_bf16(aq1, ld16(K0 + 32 + kc), sc0, 0, 0, 0);
    sc1 = __builtin_amdgcn_mfma_f32_16x16x32_bf16(aq0, ld16(K1 + kc), sc1, 0, 0, 0);
    sc1 = __builtin_amdgcn_mfma_f32_16x16x32_bf16(aq1, ld16(K1 + 32 + kc), sc1, 0, 0, 0);
  }

  unsigned short* Pw = &P[wave][0][0];
  float lsum[4];
#pragma unroll
  for (int r = 0; r < 4; ++r) {
    const int q = (kg << 2) + r;
    const int key0 = qr, key1 = 16 + qr;
    const int ka0 = i0 - 8 + key0, ka1 = i0 - 8 + key1;
    const bool v0 = (q <= key0) && (key0 <= q + 16) && (ka0 >= 0) && (ka0 < 2048);
    const bool v1 = (q <= key1) && (key1 <= q + 16) && (ka1 >= 0) && (ka1 < 2048);
    const float e0 = v0 ? __expf(sc0[r] * 0.125f) : 0.f;
    const float e1 = v1 ? __expf(sc1[r] * 0.125f) : 0.f;
    Pw[q * 40 + key0] = f2bf(e0);
    Pw[q * 40 + key1] = f2bf(e1);
    float s = e0 + e1;
#pragma unroll
    for (int off = 1; off < 16; off <<= 1) s += __shfl_xor(s, off);
    lsum[r] = s;
  }

  const bf16x8 pa = ld16(&Pw[qr * 40 + kc]);

  const int base_s = min(max(i0 - 8 + kc, 0), 2040);
  f32x4 o[4];
  const f32x4 zero = {0.f, 0.f, 0.f, 0.f};
#pragma unroll
  for (int t2 = 0; t2 < 4; ++t2) {
    const unsigned short* Vr =
        Vt + ((size_t)(bh * 64 + t2 * 16 + qr)) * 2048 + base_s;
    o[t2] = __builtin_amdgcn_mfma_f32_16x16x32_bf16(pa, ld16(Vr), zero, 0, 0, 0);
  }

  const int b = bh >> 4, h = bh & 15;
  float rinv[4];
#pragma unroll
  for (int r = 0; r < 4; ++r) rinv[r] = 1.0f / lsum[r];
#pragma unroll
  for (int t2 = 0; t2 < 4; ++t2) {
#pragma unroll
    for (int r = 0; r < 4; ++r) {
      const int q = (kg << 2) + r;
      const int d = t2 * 16 + qr;
      ctx[((size_t)(b * 2048 + i0 + q)) * 1024 + (h << 6) + d] =
          f2bf(o[t2][r] * rinv[r]);
    }
  }
}

// ---------------------------------------------------------------------------
extern "C" void kernel_launch(void* const* d_in, const int* in_sizes, int n_in,
                              void* d_out, int out_size, void* d_ws,
                              size_t ws_size, hipStream_t stream) {
  const float* x = (const float*)d_in[0];      // [2,2048,1024]
  // d_in[1] token_ids: unused by reference
  const float* w_qkv = (const float*)d_in[2];  // [3072,1024]
  const float* b_qkv = (const float*)d_in[3];  // [3072]
  const float* w_out = (const float*)d_in[4];  // [1024,1024]
  const float* b_out = (const float*)d_in[5];  // [1024]
  float* out = (float*)d_out;                  // [2,2048,1024] fp32

  char* ws = (char*)d_ws;
  unsigned short* xb    = (unsigned short*)(ws + 0);         // 8 MB
  unsigned short* wqkvb = (unsigned short*)(ws + 8388608);   // 6 MB
  unsigned short* woutb = (unsigned short*)(ws + 14680064);  // 2 MB
  unsigned short* Qb    = (unsigned short*)(ws + 16777216);  // 8 MB [bh,s,64]
  unsigned short* Kb    = (unsigned short*)(ws + 25165824);  // 8 MB [bh,s,64]
  unsigned short* Vt    = (unsigned short*)(ws + 33554432);  // 8 MB [bh,d,2048]
  unsigned short* ctxb  = (unsigned short*)(ws + 41943040);  // 8 MB [b,s,1024]

  // fp32 -> bf16 conversions, one launch (grid-stride)
  cvt_all<<<2048, 256, 0, stream>>>(x, w_qkv, w_out, xb, wqkvb, woutb);

  // QKV projection: M=4096, N=3072, K=1024 -> bf16 Q/K/Vt scatter
  // 256^2 tiles: grid 16 x 12 = 192 blocks, 512 threads
  gemm256_qkv<<<192, 512, 0, stream>>>(xb, wqkvb, b_qkv, Qb, Kb, Vt);

  // sliding attention: 4096 waves (16 queries each), 4 waves/block
  attn_mfma<<<1024, 256, 0, stream>>>(Qb, Kb, Vt, ctxb);

  // out projection: M=4096, N=1024, K=1024 -> fp32 d_out (256 blocks, gny=8)
  gemm_bt<<<256, 256, 0, stream>>>(ctxb, woutb, b_out, out, 4096, 1024, 1024, 8);
}

// Round 9
// 84.937 us; speedup vs baseline: 1.1183x; 1.1183x over previous
//
#include <hip/hip_runtime.h>
#include <stdint.h>

// ---------------------------------------------------------------------------
// SlidingAttentionModule: B=2, S=2048, D=1024, H=16, hd=64, window +-8
//   qkv = x @ w_qkv^T + b_qkv   (256x192 spill-free bf16 MFMA GEMM, full grid)
//   attn: MFMA-tiled 16-query x 32-key sliding window, no max-subtraction
//   out = ctx @ w_out^T + b_out (128^2 R5-proven bf16 MFMA GEMM, fp32 out)
// ---------------------------------------------------------------------------

typedef __bf16 bf16_t;
typedef bf16_t bf16x8 __attribute__((ext_vector_type(8)));
typedef unsigned short u16x8 __attribute__((ext_vector_type(8)));
typedef float f32x4 __attribute__((ext_vector_type(4)));

#define GLD16(g, l)                                                        \
  __builtin_amdgcn_global_load_lds(                                        \
      (const __attribute__((address_space(1))) void*)(g),                  \
      (__attribute__((address_space(3))) void*)(l), 16, 0, 0)

__device__ __forceinline__ unsigned short f2bf(float f) {
  unsigned int u = __float_as_uint(f);
  u += 0x7FFFu + ((u >> 16) & 1u);  // round-to-nearest-even
  return (unsigned short)(u >> 16);
}

__device__ __forceinline__ bf16x8 ld16(const unsigned short* p) {
  return __builtin_bit_cast(bf16x8, *reinterpret_cast<const u16x8*>(p));
}

// --- fp32 -> bf16 conversion of all three tensors, one launch ---------------
__global__ void cvt_all(const float* __restrict__ x, const float* __restrict__ wq,
                        const float* __restrict__ wo, unsigned short* __restrict__ xb,
                        unsigned short* __restrict__ wqb,
                        unsigned short* __restrict__ wob) {
  const int N0 = 1048576, N1 = 786432, N2 = 262144;  // float4 counts
  for (int i = blockIdx.x * blockDim.x + threadIdx.x; i < N0 + N1 + N2;
       i += gridDim.x * blockDim.x) {
    const float4* src;
    unsigned short* dst;
    int j;
    if (i < N0) { src = (const float4*)x; dst = xb; j = i; }
    else if (i < N0 + N1) { src = (const float4*)wq; dst = wqb; j = i - N0; }
    else { src = (const float4*)wo; dst = wob; j = i - N0 - N1; }
    const float4 f = src[j];
    ushort4 o;
    o.x = f2bf(f.x); o.y = f2bf(f.y); o.z = f2bf(f.z); o.w = f2bf(f.w);
    reinterpret_cast<ushort4*>(dst)[j] = o;
  }
}

// --- 256x192 bf16 GEMM (QKV projection), spill-free, full 256-block grid ----
// C[m,n] = sum_k A[m,k]*Bt[n,k] + bias[n]; scatter bf16 q/k [bh,s,64],
// v transposed [bh,d,2048].
// 8 waves: wr=wave>>2 (128-row half), wc=wave&3 (48-col quarter).
// Per wave: 8m x 3n frags of 16x16, acc[8][3] = 96 VGPR; ONE frag set live.
// LDS per buffer: A [256][64], B [192][64] ushort; 16B slot s of row r holds
//   global k-slot s^(r&7) (R4-proven swizzle). Stage unit r covers rows
//   [r*64, r*64+64): lane u of wave w -> row r*64+w*8+(u>>3), global slot
//   (u&7)^(u>>3); dest linear r*4096 + w*512 + u*16B. A: 4 units, B: 3.
// Pipeline (R5-proven ring): 2 buffers, 2 K-tiles in flight, counted
//   s_waitcnt vmcnt(7) at tile top (tile t+1's 7 loads stay in flight),
//   raw s_barrier pair, stage(t+2) after the read-drain barrier.
__global__ __launch_bounds__(512) void gemm_qkv(
    const unsigned short* __restrict__ A,   // [4096,1024] bf16 bits
    const unsigned short* __restrict__ Bt,  // [3072,1024] bf16 bits
    const float* __restrict__ bias,         // [3072]
    unsigned short* __restrict__ Cq, unsigned short* __restrict__ Ck,
    unsigned short* __restrict__ Cv) {
  __shared__ unsigned short sA[2][16384];
  __shared__ unsigned short sB[2][12288];

  const int K = 1024;
  const int tid = threadIdx.x;
  const int wave = tid >> 6;
  const int lane = tid & 63;
  const int bid = blockIdx.x;
  const int m0 = (bid & 15) << 8;   // 16 m-tiles of 256
  const int n0 = (bid >> 4) * 192;  // 16 n-tiles of 192

  const int wr = wave >> 2;  // 0..1
  const int wc = wave & 3;   // 0..3

  f32x4 acc[8][3] = {};

  // staging source (R4-proven mapping)
  const int srow8 = (wave << 3) + (lane >> 3);        // 0..63 within unit
  const int sslot = ((lane & 7) ^ (lane >> 3)) << 3;  // elem offset in row
  const unsigned short* Ag = A + (size_t)(m0 + srow8) * K + sslot;
  const unsigned short* Bg = Bt + (size_t)(n0 + srow8) * K + sslot;
  const int wdst = wave * 512;

  const int T = 16;  // K/64

  auto stage = [&](int t, int b) {
#pragma unroll
    for (int r = 0; r < 4; ++r)
      GLD16(Ag + (size_t)(r * 64) * K + t * 64, &sA[b][r * 4096 + wdst]);
#pragma unroll
    for (int r = 0; r < 3; ++r)
      GLD16(Bg + (size_t)(r * 64) * K + t * 64, &sB[b][r * 4096 + wdst]);
  };

  stage(0, 0);
  stage(1, 1);  // 14 loads/thread in flight

  const int kg = lane >> 4;
  const int l7 = lane & 7;
  // read bases (ushort idx); kh flips elem bit 5 (slot bit 2 ^ via swizzle)
  const int a0 = wr * 8192 + (lane & 15) * 64 + ((kg ^ l7) << 3);
  const int b0 = wc * 3072 + (lane & 15) * 64 + ((kg ^ l7) << 3);

  for (int t = 0; t < T; ++t) {
    if (t < T - 1)
      asm volatile("s_waitcnt vmcnt(7)" ::: "memory");  // tile t landed
    else
      asm volatile("s_waitcnt vmcnt(0)" ::: "memory");
    __builtin_amdgcn_s_barrier();

    const int b = t & 1;
    const unsigned short* sAb = sA[b];
    const unsigned short* sBb = sB[b];

    // ---- phase kh=0: read frags, MFMA (frag set dies before kh=1) ----
    {
      bf16x8 af[8], bf[3];
#pragma unroll
      for (int m = 0; m < 8; ++m) af[m] = ld16(&sAb[a0 + m * 1024]);
#pragma unroll
      for (int n = 0; n < 3; ++n) bf[n] = ld16(&sBb[b0 + n * 1024]);
      asm volatile("s_waitcnt lgkmcnt(0)" ::: "memory");
      __builtin_amdgcn_sched_barrier(0);
      __builtin_amdgcn_s_setprio(1);
#pragma unroll
      for (int m = 0; m < 8; ++m)
#pragma unroll
        for (int n = 0; n < 3; ++n)
          acc[m][n] = __builtin_amdgcn_mfma_f32_16x16x32_bf16(
              af[m], bf[n], acc[m][n], 0, 0, 0);
      __builtin_amdgcn_s_setprio(0);
    }

    // ---- phase kh=1: read frags, drain, barrier, prefetch, MFMA ----
    {
      bf16x8 af[8], bf[3];
#pragma unroll
      for (int m = 0; m < 8; ++m) af[m] = ld16(&sAb[(a0 ^ 32) + m * 1024]);
#pragma unroll
      for (int n = 0; n < 3; ++n) bf[n] = ld16(&sBb[(b0 ^ 32) + n * 1024]);
      asm volatile("s_waitcnt lgkmcnt(0)" ::: "memory");  // buf-b reads done
      __builtin_amdgcn_sched_barrier(0);                  // rule #18
      __builtin_amdgcn_s_barrier();  // every wave done reading buf b

      if (t + 2 < T) stage(t + 2, b);  // overwrite safe; hidden under MFMAs

      __builtin_amdgcn_s_setprio(1);
#pragma unroll
      for (int m = 0; m < 8; ++m)
#pragma unroll
        for (int n = 0; n < 3; ++n)
          acc[m][n] = __builtin_amdgcn_mfma_f32_16x16x32_bf16(
              af[m], bf[n], acc[m][n], 0, 0, 0);
      __builtin_amdgcn_s_setprio(0);
    }
  }

  // epilogue: C/D layout col = lane&15, row = (lane>>4)*4 + reg  [m89]
#pragma unroll
  for (int m = 0; m < 8; ++m) {
    const int row0 = m0 + wr * 128 + m * 16 + ((lane >> 4) << 2);
#pragma unroll
    for (int n = 0; n < 3; ++n) {
      const int col = n0 + wc * 48 + n * 16 + (lane & 15);
      const float bb = bias[col];
#pragma unroll
      for (int r = 0; r < 4; ++r) {
        const int mm = row0 + r;
        const float val = acc[m][n][r] + bb;
        const int b2 = mm >> 11, s = mm & 2047;
        const int which = col >> 10, nn = col & 1023;
        const int h = nn >> 6, d = nn & 63;
        const int bh = (b2 << 4) + h;
        const unsigned short vb = f2bf(val);
        if (which == 0)
          Cq[((size_t)(bh * 2048 + s)) * 64 + d] = vb;
        else if (which == 1)
          Ck[((size_t)(bh * 2048 + s)) * 64 + d] = vb;
        else
          Cv[((size_t)(bh * 64 + d)) * 2048 + s] = vb;
      }
    }
  }
}

// --- 128x128 R5-proven GEMM (out projection, fp32 out) ----------------------
__global__ __launch_bounds__(256, 2) void gemm_bt(
    const unsigned short* __restrict__ A,   // [M,K] bf16 bits
    const unsigned short* __restrict__ Bt,  // [N,K] bf16 bits
    const float* __restrict__ bias,         // [N]
    float* __restrict__ Cp, int M, int N, int K, int gny) {
  __shared__ unsigned short sA[2][8192];
  __shared__ unsigned short sB[2][8192];

  const int tid = threadIdx.x;
  const int wave = tid >> 6;
  const int lane = tid & 63;

  const int nwg = gridDim.x;
  const int bid = blockIdx.x;
  const int cw = (nwg >> 3) / gny;
  const int xcd = bid & 7;
  const int idx = bid >> 3;
  const int m0 = (xcd * cw + idx % cw) * 128;
  const int n0 = (idx / cw) * 128;

  const int wr = wave >> 1;
  const int wc = wave & 1;

  f32x4 acc[4][4] = {};

  const int srow = (wave << 3) + (lane >> 3);
  const int sslot = ((lane & 7) ^ (lane >> 3)) << 3;
  const unsigned short* Ag = A + (size_t)(m0 + srow) * K + sslot;
  const unsigned short* Bg = Bt + (size_t)(n0 + srow) * K + sslot;
  const int wdst = wave * 512;

  const int T = K >> 6;

  auto stage = [&](int t, int b) {
#pragma unroll
    for (int r = 0; r < 4; ++r) {
      GLD16(Ag + (size_t)(r * 32) * K + t * 64, &sA[b][r * 2048 + wdst]);
      GLD16(Bg + (size_t)(r * 32) * K + t * 64, &sB[b][r * 2048 + wdst]);
    }
  };

  stage(0, 0);
  stage(1, 1);

  const int kg = lane >> 4;
  const int l7 = lane & 7;
  const int arr = wr * 64 + (lane & 15);
  const int brr = wc * 64 + (lane & 15);

  for (int t = 0; t < T; ++t) {
    if (t < T - 1)
      asm volatile("s_waitcnt vmcnt(8)" ::: "memory");
    else
      asm volatile("s_waitcnt vmcnt(0)" ::: "memory");
    __builtin_amdgcn_s_barrier();

    const int b = t & 1;
    const unsigned short* sAb = sA[b];
    const unsigned short* sBb = sB[b];
    bf16x8 af[2][4], bfr[2][4];
#pragma unroll
    for (int st = 0; st < 2; ++st) {
#pragma unroll
      for (int f = 0; f < 4; ++f) {
        const int se = ((st << 2) | kg) ^ l7;
        af[st][f] = ld16(&sAb[(arr + f * 16) * 64 + (se << 3)]);
        bfr[st][f] = ld16(&sBb[(brr + f * 16) * 64 + (se << 3)]);
      }
    }
    asm volatile("s_waitcnt lgkmcnt(0)" ::: "memory");
    __builtin_amdgcn_sched_barrier(0);
    __builtin_amdgcn_s_barrier();

    if (t + 2 < T) stage(t + 2, b);

#pragma unroll
    for (int st = 0; st < 2; ++st)
#pragma unroll
      for (int i = 0; i < 4; ++i)
#pragma unroll
        for (int j = 0; j < 4; ++j)
          acc[i][j] = __builtin_amdgcn_mfma_f32_16x16x32_bf16(
              af[st][i], bfr[st][j], acc[i][j], 0, 0, 0);
  }

#pragma unroll
  for (int i = 0; i < 4; ++i) {
    const int row0 = m0 + wr * 64 + i * 16 + ((lane >> 4) << 2);
#pragma unroll
    for (int j = 0; j < 4; ++j) {
      const int col = n0 + wc * 64 + j * 16 + (lane & 15);
      const float bb = bias[col];
#pragma unroll
      for (int r = 0; r < 4; ++r)
        Cp[(size_t)(row0 + r) * N + col] = acc[i][j][r] + bb;
    }
  }
}

// --- MFMA sliding attention: 1 wave = 16 queries x 32-key window ------------
// Q,K: [bh, s, 64] bf16.  Vt: [bh, d, 2048] bf16.  ctx out: [b, s, 1024] bf16.
__global__ __launch_bounds__(256) void attn_mfma(
    const unsigned short* __restrict__ Qb, const unsigned short* __restrict__ Kb,
    const unsigned short* __restrict__ Vt, unsigned short* __restrict__ ctx) {
  __shared__ unsigned short P[4][16][40];  // per-wave P tile, padded stride 40
  const int wave = threadIdx.x >> 6;
  const int lane = threadIdx.x & 63;
  const int gw = (blockIdx.x << 2) + wave;
  const int bh = gw >> 7;           // 0..31
  const int i0 = (gw & 127) << 4;   // query tile start
  const int qr = lane & 15;
  const int kg = lane >> 4;         // 0..3
  const int kc = kg << 3;           // k-offset

  const size_t qbase = ((size_t)(bh * 2048 + i0 + qr)) * 64;
  const bf16x8 aq0 = ld16(Qb + qbase + kc);
  const bf16x8 aq1 = ld16(Qb + qbase + 32 + kc);

  f32x4 sc0 = {0.f, 0.f, 0.f, 0.f}, sc1 = {0.f, 0.f, 0.f, 0.f};
  {
    const int ka0 = i0 - 8 + qr;
    const int ka1 = ka0 + 16;
    const int kcl0 = min(max(ka0, 0), 2047);
    const int kcl1 = min(max(ka1, 0), 2047);
    const unsigned short* K0 = Kb + ((size_t)(bh * 2048 + kcl0)) * 64;
    const unsigned short* K1 = Kb + ((size_t)(bh * 2048 + kcl1)) * 64;
    sc0 = __builtin_amdgcn_mfma_f32_16x16x32_bf16(aq0, ld16(K0 + kc), sc0, 0, 0, 0);
    sc0 = __builtin_amdgcn_mfma_f32_16x16x32_bf16(aq1, ld16(K0 + 32 + kc), sc0, 0, 0, 0);
    sc1 = __builtin_amdgcn_mfma_f32_16x16x32_bf16(aq0, ld16(K1 + kc), sc1, 0, 0, 0);
    sc1 = __builtin_amdgcn_mfma_f32_16x16x32_bf16(aq1, ld16(K1 + 32 + kc), sc1, 0, 0, 0);
  }

  unsigned short* Pw = &P[wave][0][0];
  float lsum[4];
#pragma unroll
  for (int r = 0; r < 4; ++r) {
    const int q = (kg << 2) + r;
    const int key0 = qr, key1 = 16 + qr;
    const int ka0 = i0 - 8 + key0, ka1 = i0 - 8 + key1;
    const bool v0 = (q <= key0) && (key0 <= q + 16) && (ka0 >= 0) && (ka0 < 2048);
    const bool v1 = (q <= key1) && (key1 <= q + 16) && (ka1 >= 0) && (ka1 < 2048);
    const float e0 = v0 ? __expf(sc0[r] * 0.125f) : 0.f;
    const float e1 = v1 ? __expf(sc1[r] * 0.125f) : 0.f;
    Pw[q * 40 + key0] = f2bf(e0);
    Pw[q * 40 + key1] = f2bf(e1);
    float s = e0 + e1;
#pragma unroll
    for (int off = 1; off < 16; off <<= 1) s += __shfl_xor(s, off);
    lsum[r] = s;
  }

  const bf16x8 pa = ld16(&Pw[qr * 40 + kc]);

  const int base_s = min(max(i0 - 8 + kc, 0), 2040);
  f32x4 o[4];
  const f32x4 zero = {0.f, 0.f, 0.f, 0.f};
#pragma unroll
  for (int t2 = 0; t2 < 4; ++t2) {
    const unsigned short* Vr =
        Vt + ((size_t)(bh * 64 + t2 * 16 + qr)) * 2048 + base_s;
    o[t2] = __builtin_amdgcn_mfma_f32_16x16x32_bf16(pa, ld16(Vr), zero, 0, 0, 0);
  }

  const int b = bh >> 4, h = bh & 15;
  float rinv[4];
#pragma unroll
  for (int r = 0; r < 4; ++r) rinv[r] = 1.0f / lsum[r];
#pragma unroll
  for (int t2 = 0; t2 < 4; ++t2) {
#pragma unroll
    for (int r = 0; r < 4; ++r) {
      const int q = (kg << 2) + r;
      const int d = t2 * 16 + qr;
      ctx[((size_t)(b * 2048 + i0 + q)) * 1024 + (h << 6) + d] =
          f2bf(o[t2][r] * rinv[r]);
    }
  }
}

// ---------------------------------------------------------------------------
extern "C" void kernel_launch(void* const* d_in, const int* in_sizes, int n_in,
                              void* d_out, int out_size, void* d_ws,
                              size_t ws_size, hipStream_t stream) {
  const float* x = (const float*)d_in[0];      // [2,2048,1024]
  // d_in[1] token_ids: unused by reference
  const float* w_qkv = (const float*)d_in[2];  // [3072,1024]
  const float* b_qkv = (const float*)d_in[3];  // [3072]
  const float* w_out = (const float*)d_in[4];  // [1024,1024]
  const float* b_out = (const float*)d_in[5];  // [1024]
  float* out = (float*)d_out;                  // [2,2048,1024] fp32

  char* ws = (char*)d_ws;
  unsigned short* xb    = (unsigned short*)(ws + 0);         // 8 MB
  unsigned short* wqkvb = (unsigned short*)(ws + 8388608);   // 6 MB
  unsigned short* woutb = (unsigned short*)(ws + 14680064);  // 2 MB
  unsigned short* Qb    = (unsigned short*)(ws + 16777216);  // 8 MB [bh,s,64]
  unsigned short* Kb    = (unsigned short*)(ws + 25165824);  // 8 MB [bh,s,64]
  unsigned short* Vt    = (unsigned short*)(ws + 33554432);  // 8 MB [bh,d,2048]
  unsigned short* ctxb  = (unsigned short*)(ws + 41943040);  // 8 MB [b,s,1024]

  // fp32 -> bf16 conversions, one launch (grid-stride)
  cvt_all<<<2048, 256, 0, stream>>>(x, w_qkv, w_out, xb, wqkvb, woutb);

  // QKV projection: M=4096, N=3072, K=1024 -> bf16 Q/K/Vt scatter
  // 256x192 tiles: 16 x 16 = 256 blocks (full CU fill), 512 threads
  gemm_qkv<<<256, 512, 0, stream>>>(xb, wqkvb, b_qkv, Qb, Kb, Vt);

  // sliding attention: 4096 waves (16 queries each), 4 waves/block
  attn_mfma<<<1024, 256, 0, stream>>>(Qb, Kb, Vt, ctxb);

  // out projection: M=4096, N=1024, K=1024 -> fp32 d_out (256 blocks, gny=8)
  gemm_bt<<<256, 256, 0, stream>>>(ctxb, woutb, b_out, out, 4096, 1024, 1024, 8);
}

// Round 10
// 79.207 us; speedup vs baseline: 1.1992x; 1.0723x over previous
//
#include <hip/hip_runtime.h>
#include <stdint.h>

// ---------------------------------------------------------------------------
// SlidingAttentionModule: B=2, S=2048, D=1024, H=16, hd=64, window +-8
//   qkv = x @ w_qkv^T + b_qkv   (128^2 BK=32 3-deep counted-vmcnt GEMM, 3/CU)
//   attn: MFMA-tiled 16-query x 32-key sliding window, no max-subtraction
//   out = ctx @ w_out^T + b_out (128^2 BK=64 2-deep R5-proven GEMM, fp32 out)
// ---------------------------------------------------------------------------

typedef __bf16 bf16_t;
typedef bf16_t bf16x8 __attribute__((ext_vector_type(8)));
typedef unsigned short u16x8 __attribute__((ext_vector_type(8)));
typedef float f32x4 __attribute__((ext_vector_type(4)));

#define GLD16(g, l)                                                        \
  __builtin_amdgcn_global_load_lds(                                        \
      (const __attribute__((address_space(1))) void*)(g),                  \
      (__attribute__((address_space(3))) void*)(l), 16, 0, 0)

__device__ __forceinline__ unsigned short f2bf(float f) {
  unsigned int u = __float_as_uint(f);
  u += 0x7FFFu + ((u >> 16) & 1u);  // round-to-nearest-even
  return (unsigned short)(u >> 16);
}

__device__ __forceinline__ bf16x8 ld16(const unsigned short* p) {
  return __builtin_bit_cast(bf16x8, *reinterpret_cast<const u16x8*>(p));
}

// --- fp32 -> bf16 conversion of all three tensors, one launch ---------------
__global__ void cvt_all(const float* __restrict__ x, const float* __restrict__ wq,
                        const float* __restrict__ wo, unsigned short* __restrict__ xb,
                        unsigned short* __restrict__ wqb,
                        unsigned short* __restrict__ wob) {
  const int N0 = 1048576, N1 = 786432, N2 = 262144;  // float4 counts
  for (int i = blockIdx.x * blockDim.x + threadIdx.x; i < N0 + N1 + N2;
       i += gridDim.x * blockDim.x) {
    const float4* src;
    unsigned short* dst;
    int j;
    if (i < N0) { src = (const float4*)x; dst = xb; j = i; }
    else if (i < N0 + N1) { src = (const float4*)wq; dst = wqb; j = i - N0; }
    else { src = (const float4*)wo; dst = wob; j = i - N0 - N1; }
    const float4 f = src[j];
    ushort4 o;
    o.x = f2bf(f.x); o.y = f2bf(f.y); o.z = f2bf(f.z); o.w = f2bf(f.w);
    reinterpret_cast<ushort4*>(dst)[j] = o;
  }
}

// --- 128x128 BK=32 3-deep QKV GEMM ------------------------------------------
// C[m,n] = sum_k A[m,k]*Bt[n,k] + bias[n]; scatter bf16 q/k [bh,s,64],
// v transposed [bh,d,2048].
// LDS: 3 buffers x (A 8KB + B 8KB) = 48 KB -> 3 blocks/CU; grid 768 fully
//   resident. Tile [128][32] ushort = rows of 4 16B-granules; granule g of
//   row r holds global k-chunk g ^ ((r>>1)&3).
// Stage (4 loads/thread/tile): unit r in {0,1}: lane u -> row r*64+wave*16
//   +(u>>2), global chunk (u&3)^((lane>>3)&3); dest linear. 4-lane clusters
//   cover one 64B row segment (permuted within) -> coalesced.
// Read: frag row = wr|wc*64 + f*16 + qr, granule kg ^ ((qr>>1)&3); satisfies
//   (row>>1)&3 == (qr>>1)&3 for all f -> returns global chunk kg. Bank-
//   uniform (8 accesses/bank = LDS floor).
// Pipeline: 3 tiles in flight (12 loads), s_waitcnt vmcnt(8) steady state
//   (vmcnt(4)/(0) at tail), raw barrier pair, stage(t+3) after read-drain.
__global__ __launch_bounds__(256) void gemm_qkv(
    const unsigned short* __restrict__ A,   // [4096,1024] bf16 bits
    const unsigned short* __restrict__ Bt,  // [3072,1024] bf16 bits
    const float* __restrict__ bias,         // [3072]
    unsigned short* __restrict__ Cq, unsigned short* __restrict__ Ck,
    unsigned short* __restrict__ Cv) {
  __shared__ unsigned short sA[3][4096];
  __shared__ unsigned short sB[3][4096];

  const int K = 1024;
  const int tid = threadIdx.x;
  const int wave = tid >> 6;
  const int lane = tid & 63;
  const int m0 = blockIdx.x << 7;  // 32 m-tiles
  const int n0 = blockIdx.y << 7;  // 24 n-tiles

  const int wr = wave >> 1;
  const int wc = wave & 1;

  f32x4 acc[4][4] = {};

  // staging source: lane u -> row wave*16+(u>>2) (+r*64), chunk (u&3)^((u>>3)&3)
  const int srow = (wave << 4) + (lane >> 2);
  const int sslot = (((lane & 3) ^ ((lane >> 3) & 3)) << 3);
  const unsigned short* Ag = A + (size_t)(m0 + srow) * K + sslot;
  const unsigned short* Bg = Bt + (size_t)(n0 + srow) * K + sslot;
  const int wdst = wave * 512;  // ushort offset; +r*2048; +lane*8 implicit

  auto stage = [&](int t, int b) {
#pragma unroll
    for (int r = 0; r < 2; ++r) {
      GLD16(Ag + (size_t)(r * 64) * K + t * 32, &sA[b][r * 2048 + wdst]);
      GLD16(Bg + (size_t)(r * 64) * K + t * 32, &sB[b][r * 2048 + wdst]);
    }
  };

  // prologue: 3 K-tiles in flight (12 loads/thread)
  stage(0, 0);
  stage(1, 1);
  stage(2, 2);

  const int qr = lane & 15;
  const int kg = lane >> 4;
  const int geff8 = ((kg ^ ((qr >> 1) & 3)) << 3);
  const int ar = wr * 64 + qr;
  const int br = wc * 64 + qr;

  for (int t = 0; t < 32; ++t) {
    // tile t must land; tiles t+1, t+2 (8 loads) stay in flight
    if (t < 30)
      asm volatile("s_waitcnt vmcnt(8)" ::: "memory");
    else if (t == 30)
      asm volatile("s_waitcnt vmcnt(4)" ::: "memory");
    else
      asm volatile("s_waitcnt vmcnt(0)" ::: "memory");
    __builtin_amdgcn_s_barrier();  // all waves' tile-t loads landed

    const int b = t % 3;
    const unsigned short* sAb = sA[b];
    const unsigned short* sBb = sB[b];

    bf16x8 af[4], bf[4];
#pragma unroll
    for (int f = 0; f < 4; ++f) {
      af[f] = ld16(&sAb[(ar + f * 16) * 32 + geff8]);
      bf[f] = ld16(&sBb[(br + f * 16) * 32 + geff8]);
    }
    asm volatile("s_waitcnt lgkmcnt(0)" ::: "memory");  // frags in regs
    __builtin_amdgcn_sched_barrier(0);                  // rule #18
    __builtin_amdgcn_s_barrier();  // all waves done reading buf b

    if (t + 3 < 32) stage(t + 3, b);  // overwrite safe; hidden by MFMAs

    __builtin_amdgcn_s_setprio(1);
#pragma unroll
    for (int i = 0; i < 4; ++i)
#pragma unroll
      for (int j = 0; j < 4; ++j)
        acc[i][j] = __builtin_amdgcn_mfma_f32_16x16x32_bf16(af[i], bf[j],
                                                            acc[i][j], 0, 0, 0);
    __builtin_amdgcn_s_setprio(0);
  }

  // epilogue: C/D layout col = lane&15, row = (lane>>4)*4 + reg  [m89]
#pragma unroll
  for (int i = 0; i < 4; ++i) {
    const int row0 = m0 + wr * 64 + i * 16 + ((lane >> 4) << 2);
#pragma unroll
    for (int j = 0; j < 4; ++j) {
      const int col = n0 + wc * 64 + j * 16 + (lane & 15);
      const float bb = bias[col];
#pragma unroll
      for (int r = 0; r < 4; ++r) {
        const int mm = row0 + r;
        const float val = acc[i][j][r] + bb;
        const int b2 = mm >> 11, s = mm & 2047;
        const int which = col >> 10, nn = col & 1023;
        const int h = nn >> 6, d = nn & 63;
        const int bh = (b2 << 4) + h;
        const unsigned short vb = f2bf(val);
        if (which == 0)
          Cq[((size_t)(bh * 2048 + s)) * 64 + d] = vb;
        else if (which == 1)
          Ck[((size_t)(bh * 2048 + s)) * 64 + d] = vb;
        else
          Cv[((size_t)(bh * 64 + d)) * 2048 + s] = vb;
      }
    }
  }
}

// --- 128x128 R5-proven GEMM (out projection, fp32 out) ----------------------
__global__ __launch_bounds__(256, 2) void gemm_bt(
    const unsigned short* __restrict__ A,   // [M,K] bf16 bits
    const unsigned short* __restrict__ Bt,  // [N,K] bf16 bits
    const float* __restrict__ bias,         // [N]
    float* __restrict__ Cp, int M, int N, int K, int gny) {
  __shared__ unsigned short sA[2][8192];
  __shared__ unsigned short sB[2][8192];

  const int tid = threadIdx.x;
  const int wave = tid >> 6;
  const int lane = tid & 63;

  const int nwg = gridDim.x;
  const int bid = blockIdx.x;
  const int cw = (nwg >> 3) / gny;
  const int xcd = bid & 7;
  const int idx = bid >> 3;
  const int m0 = (xcd * cw + idx % cw) * 128;
  const int n0 = (idx / cw) * 128;

  const int wr = wave >> 1;
  const int wc = wave & 1;

  f32x4 acc[4][4] = {};

  const int srow = (wave << 3) + (lane >> 3);
  const int sslot = ((lane & 7) ^ (lane >> 3)) << 3;
  const unsigned short* Ag = A + (size_t)(m0 + srow) * K + sslot;
  const unsigned short* Bg = Bt + (size_t)(n0 + srow) * K + sslot;
  const int wdst = wave * 512;

  const int T = K >> 6;

  auto stage = [&](int t, int b) {
#pragma unroll
    for (int r = 0; r < 4; ++r) {
      GLD16(Ag + (size_t)(r * 32) * K + t * 64, &sA[b][r * 2048 + wdst]);
      GLD16(Bg + (size_t)(r * 32) * K + t * 64, &sB[b][r * 2048 + wdst]);
    }
  };

  stage(0, 0);
  stage(1, 1);

  const int kg = lane >> 4;
  const int l7 = lane & 7;
  const int arr = wr * 64 + (lane & 15);
  const int brr = wc * 64 + (lane & 15);

  for (int t = 0; t < T; ++t) {
    if (t < T - 1)
      asm volatile("s_waitcnt vmcnt(8)" ::: "memory");
    else
      asm volatile("s_waitcnt vmcnt(0)" ::: "memory");
    __builtin_amdgcn_s_barrier();

    const int b = t & 1;
    const unsigned short* sAb = sA[b];
    const unsigned short* sBb = sB[b];
    bf16x8 af[2][4], bfr[2][4];
#pragma unroll
    for (int st = 0; st < 2; ++st) {
#pragma unroll
      for (int f = 0; f < 4; ++f) {
        const int se = ((st << 2) | kg) ^ l7;
        af[st][f] = ld16(&sAb[(arr + f * 16) * 64 + (se << 3)]);
        bfr[st][f] = ld16(&sBb[(brr + f * 16) * 64 + (se << 3)]);
      }
    }
    asm volatile("s_waitcnt lgkmcnt(0)" ::: "memory");
    __builtin_amdgcn_sched_barrier(0);
    __builtin_amdgcn_s_barrier();

    if (t + 2 < T) stage(t + 2, b);

#pragma unroll
    for (int st = 0; st < 2; ++st)
#pragma unroll
      for (int i = 0; i < 4; ++i)
#pragma unroll
        for (int j = 0; j < 4; ++j)
          acc[i][j] = __builtin_amdgcn_mfma_f32_16x16x32_bf16(
              af[st][i], bfr[st][j], acc[i][j], 0, 0, 0);
  }

#pragma unroll
  for (int i = 0; i < 4; ++i) {
    const int row0 = m0 + wr * 64 + i * 16 + ((lane >> 4) << 2);
#pragma unroll
    for (int j = 0; j < 4; ++j) {
      const int col = n0 + wc * 64 + j * 16 + (lane & 15);
      const float bb = bias[col];
#pragma unroll
      for (int r = 0; r < 4; ++r)
        Cp[(size_t)(row0 + r) * N + col] = acc[i][j][r] + bb;
    }
  }
}

// --- MFMA sliding attention: 1 wave = 16 queries x 32-key window ------------
// Q,K: [bh, s, 64] bf16.  Vt: [bh, d, 2048] bf16.  ctx out: [b, s, 1024] bf16.
__global__ __launch_bounds__(256) void attn_mfma(
    const unsigned short* __restrict__ Qb, const unsigned short* __restrict__ Kb,
    const unsigned short* __restrict__ Vt, unsigned short* __restrict__ ctx) {
  __shared__ unsigned short P[4][16][40];  // per-wave P tile, padded stride 40
  const int wave = threadIdx.x >> 6;
  const int lane = threadIdx.x & 63;
  const int gw = (blockIdx.x << 2) + wave;
  const int bh = gw >> 7;           // 0..31
  const int i0 = (gw & 127) << 4;   // query tile start
  const int qr = lane & 15;
  const int kg = lane >> 4;         // 0..3
  const int kc = kg << 3;           // k-offset

  const size_t qbase = ((size_t)(bh * 2048 + i0 + qr)) * 64;
  const bf16x8 aq0 = ld16(Qb + qbase + kc);
  const bf16x8 aq1 = ld16(Qb + qbase + 32 + kc);

  f32x4 sc0 = {0.f, 0.f, 0.f, 0.f}, sc1 = {0.f, 0.f, 0.f, 0.f};
  {
    const int ka0 = i0 - 8 + qr;
    const int ka1 = ka0 + 16;
    const int kcl0 = min(max(ka0, 0), 2047);
    const int kcl1 = min(max(ka1, 0), 2047);
    const unsigned short* K0 = Kb + ((size_t)(bh * 2048 + kcl0)) * 64;
    const unsigned short* K1 = Kb + ((size_t)(bh * 2048 + kcl1)) * 64;
    sc0 = __builtin_amdgcn_mfma_f32_16x16x32_bf16(aq0, ld16(K0 + kc), sc0, 0, 0, 0);
    sc0 = __builtin_amdgcn_mfma_f32_16x16x32_bf16(aq1, ld16(K0 + 32 + kc), sc0, 0, 0, 0);
    sc1 = __builtin_amdgcn_mfma_f32_16x16x32_bf16(aq0, ld16(K1 + kc), sc1, 0, 0, 0);
    sc1 = __builtin_amdgcn_mfma_f32_16x16x32_bf16(aq1, ld16(K1 + 32 + kc), sc1, 0, 0, 0);
  }

  unsigned short* Pw = &P[wave][0][0];
  float lsum[4];
#pragma unroll
  for (int r = 0; r < 4; ++r) {
    const int q = (kg << 2) + r;
    const int key0 = qr, key1 = 16 + qr;
    const int ka0 = i0 - 8 + key0, ka1 = i0 - 8 + key1;
    const bool v0 = (q <= key0) && (key0 <= q + 16) && (ka0 >= 0) && (ka0 < 2048);
    const bool v1 = (q <= key1) && (key1 <= q + 16) && (ka1 >= 0) && (ka1 < 2048);
    const float e0 = v0 ? __expf(sc0[r] * 0.125f) : 0.f;
    const float e1 = v1 ? __expf(sc1[r] * 0.125f) : 0.f;
    Pw[q * 40 + key0] = f2bf(e0);
    Pw[q * 40 + key1] = f2bf(e1);
    float s = e0 + e1;
#pragma unroll
    for (int off = 1; off < 16; off <<= 1) s += __shfl_xor(s, off);
    lsum[r] = s;
  }

  const bf16x8 pa = ld16(&Pw[qr * 40 + kc]);

  const int base_s = min(max(i0 - 8 + kc, 0), 2040);
  f32x4 o[4];
  const f32x4 zero = {0.f, 0.f, 0.f, 0.f};
#pragma unroll
  for (int t2 = 0; t2 < 4; ++t2) {
    const unsigned short* Vr =
        Vt + ((size_t)(bh * 64 + t2 * 16 + qr)) * 2048 + base_s;
    o[t2] = __builtin_amdgcn_mfma_f32_16x16x32_bf16(pa, ld16(Vr), zero, 0, 0, 0);
  }

  const int b = bh >> 4, h = bh & 15;
  float rinv[4];
#pragma unroll
  for (int r = 0; r < 4; ++r) rinv[r] = 1.0f / lsum[r];
#pragma unroll
  for (int t2 = 0; t2 < 4; ++t2) {
#pragma unroll
    for (int r = 0; r < 4; ++r) {
      const int q = (kg << 2) + r;
      const int d = t2 * 16 + qr;
      ctx[((size_t)(b * 2048 + i0 + q)) * 1024 + (h << 6) + d] =
          f2bf(o[t2][r] * rinv[r]);
    }
  }
}

// ---------------------------------------------------------------------------
extern "C" void kernel_launch(void* const* d_in, const int* in_sizes, int n_in,
                              void* d_out, int out_size, void* d_ws,
                              size_t ws_size, hipStream_t stream) {
  const float* x = (const float*)d_in[0];      // [2,2048,1024]
  // d_in[1] token_ids: unused by reference
  const float* w_qkv = (const float*)d_in[2];  // [3072,1024]
  const float* b_qkv = (const float*)d_in[3];  // [3072]
  const float* w_out = (const float*)d_in[4];  // [1024,1024]
  const float* b_out = (const float*)d_in[5];  // [1024]
  float* out = (float*)d_out;                  // [2,2048,1024] fp32

  char* ws = (char*)d_ws;
  unsigned short* xb    = (unsigned short*)(ws + 0);         // 8 MB
  unsigned short* wqkvb = (unsigned short*)(ws + 8388608);   // 6 MB
  unsigned short* woutb = (unsigned short*)(ws + 14680064);  // 2 MB
  unsigned short* Qb    = (unsigned short*)(ws + 16777216);  // 8 MB [bh,s,64]
  unsigned short* Kb    = (unsigned short*)(ws + 25165824);  // 8 MB [bh,s,64]
  unsigned short* Vt    = (unsigned short*)(ws + 33554432);  // 8 MB [bh,d,2048]
  unsigned short* ctxb  = (unsigned short*)(ws + 41943040);  // 8 MB [b,s,1024]

  // fp32 -> bf16 conversions, one launch (grid-stride)
  cvt_all<<<2048, 256, 0, stream>>>(x, w_qkv, w_out, xb, wqkvb, woutb);

  // QKV projection: M=4096, N=3072, K=1024 -> bf16 Q/K/Vt scatter
  // 128^2 tiles, 48 KB LDS -> 3 blocks/CU, all 768 blocks resident
  gemm_qkv<<<dim3(32, 24), 256, 0, stream>>>(xb, wqkvb, b_qkv, Qb, Kb, Vt);

  // sliding attention: 4096 waves (16 queries each), 4 waves/block
  attn_mfma<<<1024, 256, 0, stream>>>(Qb, Kb, Vt, ctxb);

  // out projection: M=4096, N=1024, K=1024 -> fp32 d_out (256 blocks, gny=8)
  gemm_bt<<<256, 256, 0, stream>>>(ctxb, woutb, b_out, out, 4096, 1024, 1024, 8);
}